// Round 2
// baseline (246.489 us; speedup 1.0000x reference)
//
#include <hip/hip_runtime.h>

typedef unsigned short u16;
typedef unsigned int u32;
typedef short bf16x8 __attribute__((ext_vector_type(8)));
typedef float f32x4 __attribute__((ext_vector_type(4)));

#define NAG 32
#define STATE 512
#define EMBED 64
#define TB 32   // samples per block

// d_ws bf16 layout (u16 element offsets)
#define OFF_W1L1 0
#define OFF_W2L1 32768
#define OFF_B1W  65536
#define OFF_B2L1 98304
#define OFF_W1L2 131072
#define OFF_W2L2 262144
#define WS_TOTAL 266240

__device__ __forceinline__ float bf2f(u16 u) {
    u32 i = ((u32)u) << 16; float f;
    __builtin_memcpy(&f, &i, 4); return f;
}
__device__ __forceinline__ u16 f2bf(float f) {
    u32 i; __builtin_memcpy(&i, &f, 4);
    return (u16)((i + 0x8000u) >> 16);   // round half away from zero
}
__device__ __forceinline__ bf16x8 ld8(const u16* p) {
    return *reinterpret_cast<const bf16x8*>(p);
}
// load 8 contiguous f32, pack to bf16x8
__device__ __forceinline__ bf16x8 cvt8(const float* p) {
    f32x4 a = *reinterpret_cast<const f32x4*>(p);
    f32x4 b = *reinterpret_cast<const f32x4*>(p + 4);
    bf16x8 r;
#pragma unroll
    for (int i = 0; i < 4; ++i) r[i]     = (short)f2bf(a[i]);
#pragma unroll
    for (int i = 0; i < 4; ++i) r[i + 4] = (short)f2bf(b[i]);
    return r;
}

__global__ __launch_bounds__(256) void cvt_weights(
    const float* __restrict__ w1l1w, const float* __restrict__ w2l1w,
    const float* __restrict__ b1w,   const float* __restrict__ b2l1w,
    const float* __restrict__ w1l2w, const float* __restrict__ w2l2w,
    u16* __restrict__ ws)
{
    int idx = blockIdx.x * 256 + threadIdx.x;
    const float* src; int off;
    if      (idx < OFF_W2L1)  { src = w1l1w; off = OFF_W1L1; }
    else if (idx < OFF_B1W)   { src = w2l1w; off = OFF_W2L1; }
    else if (idx < OFF_B2L1)  { src = b1w;   off = OFF_B1W;  }
    else if (idx < OFF_W1L2)  { src = b2l1w; off = OFF_B2L1; }
    else if (idx < OFF_W2L2)  { src = w1l2w; off = OFF_W1L2; }
    else if (idx < WS_TOTAL)  { src = w2l2w; off = OFF_W2L2; }
    else return;
    ws[idx] = f2bf(src[idx - off]);
}

__global__ __launch_bounds__(256) void qmix_kernel(
    const float* __restrict__ qs,    const float* __restrict__ st,
    const u16*  __restrict__ wsb,
    const float* __restrict__ w1l1b, const float* __restrict__ w1l2b,
    const float* __restrict__ w2l1b, const float* __restrict__ w2l2b,
    const float* __restrict__ b1b,   const float* __restrict__ b2l1b,
    const float* __restrict__ b2l2w, const float* __restrict__ b2l2b,
    float* __restrict__ out)
{
    // Y columns: [0:64) h1(relu), [64:128) h2(relu), [128:192) b1v(linear), [192:256) hb(relu)
    __shared__ u16  y[TB][264];     // bf16
    __shared__ u16  hid[TB][72];    // hidden bf16
    __shared__ float qsl[TB][33];   // agent_qs f32
    __shared__ float qacc[TB][2];

    const int t    = threadIdx.x;
    const int wave = t >> 6, lane = t & 63;
    const int m = lane & 15, quad = lane >> 4;
    const int sbase = blockIdx.x * TB;

    // ---- stage qs ----
    for (int i = t; i < TB * NAG; i += 256) {
        int s = i >> 5, a = i & 31;
        qsl[s][a] = qs[(size_t)(sbase + s) * NAG + a];
    }

    // ---- Phase A: Y[32][256] = states @ Wcat^T (+bias, act) ----
    const int shalf = wave >> 1, fhalf = wave & 1;
    const int s0 = shalf * 16;
    const u16* wl1[4] = { wsb + OFF_W1L1, wsb + OFF_W2L1, wsb + OFF_B1W, wsb + OFF_B2L1 };
    const float* bl1[4] = { w1l1b, w2l1b, b1b, b2l1b };

    const float* strow = st + (size_t)(sbase + s0 + m) * STATE;
    const u16* brow[8];
#pragma unroll
    for (int tt = 0; tt < 8; ++tt) {
        int grp = fhalf * 2 + (tt >> 2);
        int row = (tt & 3) * 16 + m;
        brow[tt] = wl1[grp] + (size_t)row * STATE;
    }

    f32x4 acc[8] = {};
    for (int ks = 0; ks < 16; ++ks) {
        int ko = ks * 32 + quad * 8;
        bf16x8 af = cvt8(strow + ko);
#pragma unroll
        for (int tt = 0; tt < 8; ++tt) {
            bf16x8 bf = ld8(brow[tt] + ko);
            acc[tt] = __builtin_amdgcn_mfma_f32_16x16x32_bf16(af, bf, acc[tt], 0, 0, 0);
        }
    }
#pragma unroll
    for (int tt = 0; tt < 8; ++tt) {
        int grp = fhalf * 2 + (tt >> 2);
        int row = (tt & 3) * 16 + m;
        int fcol = fhalf * 128 + tt * 16 + m;
        float bias = bl1[grp][row];
        bool isrelu = (grp != 2);
#pragma unroll
        for (int r = 0; r < 4; ++r) {
            float v = acc[tt][r] + bias;
            if (isrelu) v = fmaxf(v, 0.f);
            y[s0 + quad * 4 + r][fcol] = f2bf(v);
        }
    }
    __syncthreads();

    // ---- Phase B: hidden = elu(sum_a qs[s,a]*|h1 @ W1l2[a]^T + b| + b1v) ----
    const int e0 = (wave & 1) * 32;
    bf16x8 haf[2];
#pragma unroll
    for (int ks = 0; ks < 2; ++ks)
        haf[ks] = *reinterpret_cast<const bf16x8*>(&y[s0 + m][ks * 32 + quad * 8]);

    const u16* w1l2 = wsb + OFF_W1L2;
    f32x4 hacc[2] = {};
    for (int a = 0; a < NAG; ++a) {
        float qv[4];
#pragma unroll
        for (int r = 0; r < 4; ++r) qv[r] = qsl[s0 + quad * 4 + r][a];
#pragma unroll
        for (int tile = 0; tile < 2; ++tile) {
            const u16* rowp = w1l2 + (size_t)(a * EMBED + e0 + tile * 16 + m) * EMBED;
            f32x4 p = {};
#pragma unroll
            for (int ks = 0; ks < 2; ++ks) {
                bf16x8 bf = ld8(rowp + ks * 32 + quad * 8);
                p = __builtin_amdgcn_mfma_f32_16x16x32_bf16(haf[ks], bf, p, 0, 0, 0);
            }
            float bias = w1l2b[a * EMBED + e0 + tile * 16 + m];
#pragma unroll
            for (int r = 0; r < 4; ++r)
                hacc[tile][r] += qv[r] * fabsf(p[r] + bias);
        }
    }
#pragma unroll
    for (int tile = 0; tile < 2; ++tile) {
#pragma unroll
        for (int r = 0; r < 4; ++r) {
            int s = s0 + quad * 4 + r, e = e0 + tile * 16 + m;
            float v = hacc[tile][r] + bf2f(y[s][128 + e]);
            v = (v > 0.f) ? v : (__expf(v) - 1.f);
            hid[s][e] = f2bf(v);
        }
    }
    __syncthreads();

    // ---- Phase C: w2 = |h2 @ W2l2^T + b|; partial q = sum_e hidden*w2 ----
    bf16x8 h2f[2];
#pragma unroll
    for (int ks = 0; ks < 2; ++ks)
        h2f[ks] = *reinterpret_cast<const bf16x8*>(&y[s0 + m][64 + ks * 32 + quad * 8]);

    const u16* w2l2 = wsb + OFF_W2L2;
    f32x4 qp = {};
#pragma unroll
    for (int tp = 0; tp < 2; ++tp) {
        int etile = (wave & 1) * 2 + tp;
        const u16* rowp = w2l2 + (size_t)(etile * 16 + m) * EMBED;
        f32x4 p = {};
#pragma unroll
        for (int ks = 0; ks < 2; ++ks) {
            bf16x8 bf = ld8(rowp + ks * 32 + quad * 8);
            p = __builtin_amdgcn_mfma_f32_16x16x32_bf16(h2f[ks], bf, p, 0, 0, 0);
        }
        float bias = w2l2b[etile * 16 + m];
#pragma unroll
        for (int r = 0; r < 4; ++r) {
            float w2v = fabsf(p[r] + bias);
            float hv = bf2f(hid[s0 + quad * 4 + r][etile * 16 + m]);
            qp[r] += hv * w2v;
        }
    }
#pragma unroll
    for (int off = 1; off < 16; off <<= 1) {
#pragma unroll
        for (int r = 0; r < 4; ++r) qp[r] += __shfl_xor(qp[r], off, 64);
    }
    if (m == 0) {
#pragma unroll
        for (int r = 0; r < 4; ++r) qacc[s0 + quad * 4 + r][wave & 1] = qp[r];
    }
    __syncthreads();

    // ---- Phase D: b2 + final sum ----
    if (t < TB) {
        int s = t;
        float q = qacc[s][0] + qacc[s][1];
        float b2 = b2l2b[0];
        for (int k = 0; k < EMBED; ++k)
            b2 += bf2f(y[s][192 + k]) * b2l2w[k];
        out[sbase + s] = q + b2;
    }
}

extern "C" void kernel_launch(void* const* d_in, const int* in_sizes, int n_in,
                              void* d_out, int out_size, void* d_ws, size_t ws_size,
                              hipStream_t stream)
{
    const float* qs    = (const float*)d_in[0];
    const float* st    = (const float*)d_in[1];
    const float* w1l1w = (const float*)d_in[2];
    const float* w1l1b = (const float*)d_in[3];
    const float* w1l2w = (const float*)d_in[4];
    const float* w1l2b = (const float*)d_in[5];
    const float* w2l1w = (const float*)d_in[6];
    const float* w2l1b = (const float*)d_in[7];
    const float* w2l2w = (const float*)d_in[8];
    const float* w2l2b = (const float*)d_in[9];
    const float* b1w   = (const float*)d_in[10];
    const float* b1b   = (const float*)d_in[11];
    const float* b2l1w = (const float*)d_in[12];
    const float* b2l1b = (const float*)d_in[13];
    const float* b2l2w = (const float*)d_in[14];
    const float* b2l2b = (const float*)d_in[15];

    u16* wsb = (u16*)d_ws;

    cvt_weights<<<(WS_TOTAL + 255) / 256, 256, 0, stream>>>(
        w1l1w, w2l1w, b1w, b2l1w, w1l2w, w2l2w, wsb);

    int B = in_sizes[0] / NAG;        // 32768
    int grid = B / TB;                // 1024
    qmix_kernel<<<grid, 256, 0, stream>>>(
        qs, st, wsb,
        w1l1b, w1l2b, w2l1b, w2l2b, b1b, b2l1b, b2l2w, b2l2b,
        (float*)d_out);
}